// Round 6
// baseline (248.911 us; speedup 1.0000x reference)
//
#include <hip/hip_runtime.h>

typedef unsigned short u16;
typedef unsigned int u32;
typedef __bf16 bf16x8 __attribute__((ext_vector_type(8)));
typedef float floatx4 __attribute__((ext_vector_type(4)));

#define BB 2
#define TT 2048
#define DD 1024
#define HH 16
#define DKK 64
#define ACT (BB * TT * DD)      // 4194304 elements
#define WTE (DD * DD)           // 1048576 elements

__device__ inline u16 f2bf(float f) {
    union { float f; u32 u; } c; c.f = f;
    u32 r = (c.u + 0x7fffu + ((c.u >> 16) & 1u)) >> 16;
    return (u16)r;
}
__device__ inline u32 pack2bf(float a, float b) {
    return (u32)f2bf(a) | ((u32)f2bf(b) << 16);
}

// async global->LDS, 16B per lane; LDS dest = wave-uniform base + lane*16
typedef __attribute__((address_space(1))) const u32 gas_u32;
typedef __attribute__((address_space(3))) u32 las_u32;
__device__ __forceinline__ void gl2lds16(const u16* g, u16* l) {
    __builtin_amdgcn_global_load_lds((gas_u32*)g, (las_u32*)l, 16, 0, 0);
}

// pack 2 f32 -> 1 u32 of 2 bf16 (RNE), single VALU op (guide T12 recipe)
__device__ __forceinline__ u32 cvtpk_bf16(float lo, float hi) {
    u32 r;
    asm("v_cvt_pk_bf16_f32 %0, %1, %2" : "=v"(r) : "v"(lo), "v"(hi));
    return r;
}

// swap32 then swap16 between two VGPRs (quad = 16-lane group):
//   after: a = {a.q0, a.q2, b.q0, b.q2}, b = {a.q1, a.q3, b.q1, b.q3}
// s_nop guards the VALU->permlane wait-state conservatively.
__device__ __forceinline__ void quad_gather(u32 &a, u32 &b) {
    asm volatile("s_nop 1\n\t"
                 "v_permlane32_swap_b32 %0, %1\n\t"
                 "s_nop 1\n\t"
                 "v_permlane16_swap_b32 %0, %1"
                 : "+v"(a), "+v"(b));
}

// ---------------- fp32 -> bf16 convert pass ----------------
// t=0..2: activations (256 blocks x 16384 floats); t=3..6: weights (64 blocks)
struct CvtArgs { const float* src[7]; u16* dst[7]; };
__global__ __launch_bounds__(256) void convert_bf16(CvtArgs a) {
    int bid = blockIdx.x, t, local;
    if (bid < 768) { t = bid >> 8; local = bid & 255; }
    else { int r = bid - 768; t = 3 + (r >> 6); local = r & 63; }
    const float* s = a.src[t];
    u16* d = a.dst[t];
    const int base = local * 16384;
    for (int i = 0; i < 8; i++) {
        const int idx = base + i * 2048 + threadIdx.x * 8;
        float4 x0 = *(const float4*)(s + idx);
        float4 x1 = *(const float4*)(s + idx + 4);
        uint4 p;
        p.x = pack2bf(x0.x, x0.y); p.y = pack2bf(x0.z, x0.w);
        p.z = pack2bf(x1.x, x1.y); p.w = pack2bf(x1.z, x1.w);
        *(uint4*)(d + idx) = p;
    }
}

// ---------------- fused QKV projection (m97-style staging) ----------------
// all-bf16 A[4096,1024] x W[1024,1024]^T; unpadded 128x32 LDS tiles via
// global_load_lds width=16. z=0:Q z=1:K -> ws[b][h][t][dk]; z=2:V -> [b][h][dk][t]
__global__ __launch_bounds__(256) void qkv_gemm(
    const u16* __restrict__ Qc, const u16* __restrict__ Kc,
    const u16* __restrict__ Vc,
    const u16* __restrict__ Wqc, const u16* __restrict__ Wkc,
    const u16* __restrict__ Wvc,
    const float* __restrict__ bq, const float* __restrict__ bk,
    const float* __restrict__ bv,
    u16* __restrict__ ws)
{
    __shared__ __align__(16) u16 As[128 * 32];
    __shared__ __align__(16) u16 Bs[128 * 32];
    const int z = blockIdx.z;
    const u16* A = (z == 0) ? Qc : (z == 1) ? Kc : Vc;
    const u16* W = (z == 0) ? Wqc : (z == 1) ? Wkc : Wvc;
    const float* bias = (z == 0) ? bq : (z == 1) ? bk : bv;
    u16* out = ws + (size_t)z * (size_t)BB * HH * TT * DKK;

    const int tid  = threadIdx.x;
    const int wave = tid >> 6, lane = tid & 63;
    const int quad = lane >> 4, l16 = lane & 15;
    const int wm = wave & 1, wn = wave >> 1;
    const int m0 = blockIdx.y * 128, n0 = blockIdx.x * 128;
    const int K = DD;

    // staging: call j covers rows j*64 + wave*16 .. +15; lane -> (row=l>>2, col=(l&3)*8)
    const int lrow = lane >> 2, lcol = (lane & 3) * 8;
    const u16* Ag0 = A + (size_t)(m0 + wave * 16 + lrow) * K + lcol;
    const u16* Ag1 = A + (size_t)(m0 + 64 + wave * 16 + lrow) * K + lcol;
    const u16* Wg0 = W + (size_t)(n0 + wave * 16 + lrow) * K + lcol;
    const u16* Wg1 = W + (size_t)(n0 + 64 + wave * 16 + lrow) * K + lcol;
    u16* AsD0 = &As[(wave * 16) * 32];
    u16* AsD1 = &As[(64 + wave * 16) * 32];
    u16* BsD0 = &Bs[(wave * 16) * 32];
    u16* BsD1 = &Bs[(64 + wave * 16) * 32];

    floatx4 acc[4][4];
    for (int i = 0; i < 4; i++)
        for (int j = 0; j < 4; j++)
            acc[i][j] = floatx4{0.f, 0.f, 0.f, 0.f};

    for (int k0 = 0; k0 < K; k0 += 32) {
        __syncthreads();
        gl2lds16(Ag0 + k0, AsD0);
        gl2lds16(Ag1 + k0, AsD1);
        gl2lds16(Wg0 + k0, BsD0);
        gl2lds16(Wg1 + k0, BsD1);
        __syncthreads();   // compiler emits vmcnt(0) drain before barrier

        bf16x8 af[4], bfr[4];
        for (int mi = 0; mi < 4; mi++)
            af[mi] = *(const bf16x8*)&As[(wm * 64 + mi * 16 + l16) * 32 + quad * 8];
        for (int ni = 0; ni < 4; ni++)
            bfr[ni] = *(const bf16x8*)&Bs[(wn * 64 + ni * 16 + l16) * 32 + quad * 8];
        for (int mi = 0; mi < 4; mi++)
            for (int ni = 0; ni < 4; ni++)
                acc[mi][ni] = __builtin_amdgcn_mfma_f32_16x16x32_bf16(
                    af[mi], bfr[ni], acc[mi][ni], 0, 0, 0);
    }

    for (int ni = 0; ni < 4; ni++) {
        const int n = n0 + wn * 64 + ni * 16 + l16;
        const float bv2 = bias[n];
        for (int mi = 0; mi < 4; mi++) {
            for (int vv = 0; vv < 4; vv++) {
                const int m = m0 + wm * 64 + mi * 16 + quad * 4 + vv;
                const float val = acc[mi][ni][vv] + bv2;
                const int b = m >> 11, t = m & 2047, h = n >> 6, dk = n & 63;
                if (z == 2)
                    out[(((size_t)(b * HH + h)) * DKK + dk) * TT + t] = f2bf(val);
                else
                    out[(((size_t)(b * HH + h)) * TT + t) * DKK + dk] = f2bf(val);
            }
        }
    }
}

// ---------------- output projection (m97-style staging) ----------------
__global__ __launch_bounds__(256) void out_gemm(
    const u16* __restrict__ Av, const u16* __restrict__ Wv,
    const float* __restrict__ bias, float* __restrict__ outv)
{
    __shared__ __align__(16) u16 As[128 * 32];
    __shared__ __align__(16) u16 Bs[128 * 32];
    const int tid  = threadIdx.x;
    const int wave = tid >> 6, lane = tid & 63;
    const int quad = lane >> 4, l16 = lane & 15;
    const int wm = wave & 1, wn = wave >> 1;
    const int m0 = blockIdx.y * 128, n0 = blockIdx.x * 128;
    const int K = DD, N = DD;

    const int lrow = lane >> 2, lcol = (lane & 3) * 8;
    const u16* Ag0 = Av + (size_t)(m0 + wave * 16 + lrow) * K + lcol;
    const u16* Ag1 = Av + (size_t)(m0 + 64 + wave * 16 + lrow) * K + lcol;
    const u16* Wg0 = Wv + (size_t)(n0 + wave * 16 + lrow) * K + lcol;
    const u16* Wg1 = Wv + (size_t)(n0 + 64 + wave * 16 + lrow) * K + lcol;
    u16* AsD0 = &As[(wave * 16) * 32];
    u16* AsD1 = &As[(64 + wave * 16) * 32];
    u16* BsD0 = &Bs[(wave * 16) * 32];
    u16* BsD1 = &Bs[(64 + wave * 16) * 32];

    floatx4 acc[4][4];
    for (int i = 0; i < 4; i++)
        for (int j = 0; j < 4; j++)
            acc[i][j] = floatx4{0.f, 0.f, 0.f, 0.f};

    for (int k0 = 0; k0 < K; k0 += 32) {
        __syncthreads();
        gl2lds16(Ag0 + k0, AsD0);
        gl2lds16(Ag1 + k0, AsD1);
        gl2lds16(Wg0 + k0, BsD0);
        gl2lds16(Wg1 + k0, BsD1);
        __syncthreads();

        bf16x8 af[4], bfr[4];
        for (int mi = 0; mi < 4; mi++)
            af[mi] = *(const bf16x8*)&As[(wm * 64 + mi * 16 + l16) * 32 + quad * 8];
        for (int ni = 0; ni < 4; ni++)
            bfr[ni] = *(const bf16x8*)&Bs[(wn * 64 + ni * 16 + l16) * 32 + quad * 8];
        for (int mi = 0; mi < 4; mi++)
            for (int ni = 0; ni < 4; ni++)
                acc[mi][ni] = __builtin_amdgcn_mfma_f32_16x16x32_bf16(
                    af[mi], bfr[ni], acc[mi][ni], 0, 0, 0);
    }

    for (int ni = 0; ni < 4; ni++) {
        const int n = n0 + wn * 64 + ni * 16 + l16;
        const float bv2 = bias[n];
        for (int mi = 0; mi < 4; mi++)
            for (int vv = 0; vv < 4; vv++) {
                const int m = m0 + wm * 64 + mi * 16 + quad * 4 + vv;
                outv[(size_t)m * N + n] = acc[mi][ni][vv] + bv2;
            }
    }
}

// ---------------- flash attention: 8 waves x 32 q-rows, dbuf K/V ----------
// grid = B*H*(T/256) = 256 blocks x 512 thr (1 block/CU, 16 waves/CU).
// K/V staged direct via global_load_lds into double-buffered linear [64][64]
// tiles; ONE barrier per tile-step (prefetch t+1 issued before compute of t,
// retired by the barrier's vmcnt(0) drain -> full compute phase of latency
// hiding). Linear dest forces 128B row stride; 16-way bank conflict broken by
// XOR granule swizzle (rule #21): LDS[r][g] holds global[r][g^(r&7)], reads
// use the same XOR. P stays in-register (cvt_pk + permlane gather).
__global__ __launch_bounds__(512) void attn_kernel(
    const u16* __restrict__ Qp, const u16* __restrict__ Kp,
    const u16* __restrict__ Vpt, const int* __restrict__ mask,
    u16* __restrict__ Xa)
{
    constexpr int NT = TT / 64;   // 32 key tiles
    __shared__ __align__(16) u16 Ks[2][64 * 64];   // [buf][key][dk] swizzled
    __shared__ __align__(16) u16 Vs[2][64 * 64];   // [buf][dk][key] swizzled
    const int tid  = threadIdx.x;
    const int wave = tid >> 6, lane = tid & 63;
    const int quad = lane >> 4, l16 = lane & 15;
    const int bid = blockIdx.x;
    const int qt = bid & 7, bh = bid >> 3;
    const int b = bh >> 4, h = bh & 15;
    const int qbase = qt * 256 + wave * 32;

    const u16* Qb = Qp + (size_t)bh * TT * DKK;
    const u16* Kb = Kp + (size_t)bh * TT * DKK;
    const u16* Vb = Vpt + (size_t)bh * DKK * TT;
    const int* mk = mask + b * TT;

    // staging: 512 thr = 64 rows x 8 granules(16B). Linear LDS dest (wave w
    // writes bytes w*1024 + lane*16 = row*128 + g*16); SOURCE granule
    // pre-swizzled so LDS[r][g] = global[r][g ^ (r&7)].
    const int srow = tid >> 3, sg = tid & 7;
    const int sgs = sg ^ (srow & 7);
    const u16* Ksrc = Kb + (size_t)srow * DKK + sgs * 8;
    const u16* Vsrc = Vb + (size_t)srow * TT + sgs * 8;

    // swizzled read offsets (u16) within a 64-u16 row; frag rows have
    // row&7 == l16&7 (rows are l16 + multiple of 16)
    const int x7 = l16 & 7;
    const int rg0 = (quad ^ x7) * 8;          // granule j = quad   (dk/key 0-31)
    const int rg1 = ((quad + 4) ^ x7) * 8;    // granule j = quad+4 (dk/key 32-63)

    bf16x8 qf[2][2];
    #pragma unroll
    for (int mb = 0; mb < 2; mb++) {
        qf[mb][0] = *(const bf16x8*)&Qb[(size_t)(qbase + mb * 16 + l16) * DKK + quad * 8];
        qf[mb][1] = *(const bf16x8*)&Qb[(size_t)(qbase + mb * 16 + l16) * DKK + 32 + quad * 8];
    }

    floatx4 o[2][4];
    float rs[2] = {0.f, 0.f};
    for (int mb = 0; mb < 2; mb++)
        for (int i = 0; i < 4; i++)
            o[mb][i] = floatx4{0.f, 0.f, 0.f, 0.f};

    // prologue: stage tile 0 into buf 0
    gl2lds16(Ksrc, &Ks[0][wave * 512]);
    gl2lds16(Vsrc, &Vs[0][wave * 512]);
    __syncthreads();   // vmcnt(0) drain

    for (int ti = 0; ti < NT; ti++) {
        const int k0 = ti * 64;
        const int cur = ti & 1;

        // prefetch tile t+1 into the other buffer (retired at loop-end barrier)
        if (ti + 1 < NT) {
            gl2lds16(Ksrc + (size_t)(k0 + 64) * DKK, &Ks[cur ^ 1][wave * 512]);
            gl2lds16(Vsrc + (k0 + 64), &Vs[cur ^ 1][wave * 512]);
        }

        const int mv0 = mk[k0 + l16];
        const int mv1 = mk[k0 + 16 + l16];
        const int mv2 = mk[k0 + 32 + l16];
        const int mv3 = mk[k0 + 48 + l16];
        if (!__any(mv0 | mv1 | mv2 | mv3)) {   // block-uniform skip
            __syncthreads();
            continue;
        }
        const bool allv = __all(mv0 && mv1 && mv2 && mv3);

        // K-frags once per wave per tile; reused by both m-blocks
        bf16x8 kf[4][2];
        #pragma unroll
        for (int c = 0; c < 4; c++) {
            const u16* kb = &Ks[cur][(c * 16 + l16) * 64];
            kf[c][0] = *(const bf16x8*)&kb[rg0];
            kf[c][1] = *(const bf16x8*)&kb[rg1];
        }

        // per m-block: swapped QK^T (S^T in regs), exp, in-register gather
        union { u32 w[4]; bf16x8 v; } pa[2][2];
        #pragma unroll
        for (int mb = 0; mb < 2; mb++) {
            floatx4 s[4];
            #pragma unroll
            for (int c = 0; c < 4; c++) s[c] = floatx4{0.f, 0.f, 0.f, 0.f};
            #pragma unroll
            for (int c = 0; c < 4; c++) {
                s[c] = __builtin_amdgcn_mfma_f32_16x16x32_bf16(kf[c][0], qf[mb][0], s[c], 0, 0, 0);
                s[c] = __builtin_amdgcn_mfma_f32_16x16x32_bf16(kf[c][1], qf[mb][1], s[c], 0, 0, 0);
            }

            float p[4][4];
            if (allv) {
                #pragma unroll
                for (int c = 0; c < 4; c++)
                    #pragma unroll
                    for (int v = 0; v < 4; v++)
                        p[c][v] = __expf(s[c][v] * 0.125f);
            } else {
                #pragma unroll
                for (int c = 0; c < 4; c++)
                    #pragma unroll
                    for (int v = 0; v < 4; v++)
                        p[c][v] = mk[k0 + c * 16 + quad * 4 + v]
                                      ? __expf(s[c][v] * 0.125f) : 0.f;
            }
            #pragma unroll
            for (int c = 0; c < 4; c++)
                #pragma unroll
                for (int v = 0; v < 4; v++)
                    rs[mb] += p[c][v];

            u32 A0 = cvtpk_bf16(p[0][0], p[0][1]), B0 = cvtpk_bf16(p[1][0], p[1][1]);
            u32 A1 = cvtpk_bf16(p[0][2], p[0][3]), B1 = cvtpk_bf16(p[1][2], p[1][3]);
            u32 A2 = cvtpk_bf16(p[2][0], p[2][1]), B2 = cvtpk_bf16(p[3][0], p[3][1]);
            u32 A3 = cvtpk_bf16(p[2][2], p[2][3]), B3 = cvtpk_bf16(p[3][2], p[3][3]);
            quad_gather(A0, B0);
            quad_gather(A1, B1);
            quad_gather(A2, B2);
            quad_gather(A3, B3);
            pa[mb][0].w[0] = A0; pa[mb][0].w[1] = A1; pa[mb][0].w[2] = B0; pa[mb][0].w[3] = B1;  // keys 0-31
            pa[mb][1].w[0] = A2; pa[mb][1].w[1] = A3; pa[mb][1].w[2] = B2; pa[mb][1].w[3] = B3;  // keys 32-63
        }

        // PV: each V-frag pair serves both m-blocks (4 MFMAs per 2 reads)
        #pragma unroll
        for (int nb = 0; nb < 4; nb++) {
            const u16* vb = &Vs[cur][(nb * 16 + l16) * 64];
            const bf16x8 vf0 = *(const bf16x8*)&vb[rg0];
            const bf16x8 vf1 = *(const bf16x8*)&vb[rg1];
            o[0][nb] = __builtin_amdgcn_mfma_f32_16x16x32_bf16(pa[0][0].v, vf0, o[0][nb], 0, 0, 0);
            o[0][nb] = __builtin_amdgcn_mfma_f32_16x16x32_bf16(pa[0][1].v, vf1, o[0][nb], 0, 0, 0);
            o[1][nb] = __builtin_amdgcn_mfma_f32_16x16x32_bf16(pa[1][0].v, vf0, o[1][nb], 0, 0, 0);
            o[1][nb] = __builtin_amdgcn_mfma_f32_16x16x32_bf16(pa[1][1].v, vf1, o[1][nb], 0, 0, 0);
        }

        __syncthreads();   // drains prefetch vmcnt(0); all waves done with buf cur
    }

    // denom: combine the 4 quads' partials, then pull per-output-row values
    float inv[2][4];
    #pragma unroll
    for (int mb = 0; mb < 2; mb++) {
        rs[mb] += __shfl_xor(rs[mb], 16, 64);
        rs[mb] += __shfl_xor(rs[mb], 32, 64);
        #pragma unroll
        for (int v = 0; v < 4; v++)
            inv[mb][v] = 1.0f / __shfl(rs[mb], quad * 4 + v, 64);
    }

    #pragma unroll
    for (int mb = 0; mb < 2; mb++)
        #pragma unroll
        for (int nb = 0; nb < 4; nb++)
            #pragma unroll
            for (int v = 0; v < 4; v++) {
                const int t = qbase + mb * 16 + quad * 4 + v;
                Xa[((size_t)b * TT + t) * DD + h * DKK + nb * 16 + l16] =
                    f2bf(o[mb][nb][v] * inv[mb][v]);
            }
}

extern "C" void kernel_launch(void* const* d_in, const int* in_sizes, int n_in,
                              void* d_out, int out_size, void* d_ws, size_t ws_size,
                              hipStream_t stream) {
    const float* q    = (const float*)d_in[0];
    const float* k    = (const float*)d_in[1];
    const float* v    = (const float*)d_in[2];
    const int*   mask = (const int*)d_in[3];
    const float* Wq   = (const float*)d_in[4];
    const float* bq   = (const float*)d_in[5];
    const float* Wk   = (const float*)d_in[6];
    const float* bk   = (const float*)d_in[7];
    const float* Wv   = (const float*)d_in[8];
    const float* bv   = (const float*)d_in[9];
    const float* Wo   = (const float*)d_in[10];
    const float* bo   = (const float*)d_in[11];

    // ws layout (u16 elems): Qc|Kc|Vc (4M each) | Wqc|Wkc|Wvc|Woc (1M each)
    //                        | Qp|Kp|Vpt|Xa (4M each)  = 64 MB total
    u16* Qc  = (u16*)d_ws;
    u16* Kc  = Qc + (size_t)ACT;
    u16* Vc  = Kc + (size_t)ACT;
    u16* Wqc = Vc + (size_t)ACT;
    u16* Wkc = Wqc + (size_t)WTE;
    u16* Wvc = Wkc + (size_t)WTE;
    u16* Woc = Wvc + (size_t)WTE;
    u16* Qp  = Woc + (size_t)WTE;
    u16* Kp  = Qp + (size_t)ACT;
    u16* Vpt = Kp + (size_t)ACT;
    u16* Xa  = Vpt + (size_t)ACT;

    CvtArgs ca;
    ca.src[0] = q;  ca.dst[0] = Qc;
    ca.src[1] = k;  ca.dst[1] = Kc;
    ca.src[2] = v;  ca.dst[2] = Vc;
    ca.src[3] = Wq; ca.dst[3] = Wqc;
    ca.src[4] = Wk; ca.dst[4] = Wkc;
    ca.src[5] = Wv; ca.dst[5] = Wvc;
    ca.src[6] = Wo; ca.dst[6] = Woc;
    convert_bf16<<<1024, 256, 0, stream>>>(ca);

    qkv_gemm<<<dim3(DD / 128, (BB * TT) / 128, 3), 256, 0, stream>>>(
        Qc, Kc, Vc, Wqc, Wkc, Wvc, bq, bk, bv, Qp);

    attn_kernel<<<dim3(BB * HH * (TT / 256)), 512, 0, stream>>>(Qp, Kp, Vpt, mask, Xa);

    out_gemm<<<dim3(DD / 128, (BB * TT) / 128), 256, 0, stream>>>(Xa, Woc, bo, (float*)d_out);
}

// Round 7
// 245.496 us; speedup vs baseline: 1.0139x; 1.0139x over previous
//
#include <hip/hip_runtime.h>

typedef unsigned short u16;
typedef unsigned int u32;
typedef __bf16 bf16x8 __attribute__((ext_vector_type(8)));
typedef float floatx4 __attribute__((ext_vector_type(4)));

#define BB 2
#define TT 2048
#define DD 1024
#define HH 16
#define DKK 64
#define ACT (BB * TT * DD)      // 4194304 elements
#define WTE (DD * DD)           // 1048576 elements

__device__ inline u16 f2bf(float f) {
    union { float f; u32 u; } c; c.f = f;
    u32 r = (c.u + 0x7fffu + ((c.u >> 16) & 1u)) >> 16;
    return (u16)r;
}
__device__ inline u32 pack2bf(float a, float b) {
    return (u32)f2bf(a) | ((u32)f2bf(b) << 16);
}

// async global->LDS, 16B per lane; LDS dest = wave-uniform base + lane*16
typedef __attribute__((address_space(1))) const u32 gas_u32;
typedef __attribute__((address_space(3))) u32 las_u32;
__device__ __forceinline__ void gl2lds16(const u16* g, u16* l) {
    __builtin_amdgcn_global_load_lds((gas_u32*)g, (las_u32*)l, 16, 0, 0);
}

// pack 2 f32 -> 1 u32 of 2 bf16 (RNE), single VALU op (guide T12 recipe)
__device__ __forceinline__ u32 cvtpk_bf16(float lo, float hi) {
    u32 r;
    asm("v_cvt_pk_bf16_f32 %0, %1, %2" : "=v"(r) : "v"(lo), "v"(hi));
    return r;
}

// swap32 then swap16 between two VGPRs (quad = 16-lane group):
//   after: a = {a.q0, a.q2, b.q0, b.q2}, b = {a.q1, a.q3, b.q1, b.q3}
// s_nop guards the VALU->permlane wait-state conservatively.
__device__ __forceinline__ void quad_gather(u32 &a, u32 &b) {
    asm volatile("s_nop 1\n\t"
                 "v_permlane32_swap_b32 %0, %1\n\t"
                 "s_nop 1\n\t"
                 "v_permlane16_swap_b32 %0, %1"
                 : "+v"(a), "+v"(b));
}

// ---------------- fp32 -> bf16 convert pass ----------------
// t=0..2: activations (256 blocks x 16384 floats); t=3..6: weights (64 blocks)
struct CvtArgs { const float* src[7]; u16* dst[7]; };
__global__ __launch_bounds__(256) void convert_bf16(CvtArgs a) {
    int bid = blockIdx.x, t, local;
    if (bid < 768) { t = bid >> 8; local = bid & 255; }
    else { int r = bid - 768; t = 3 + (r >> 6); local = r & 63; }
    const float* s = a.src[t];
    u16* d = a.dst[t];
    const int base = local * 16384;
    for (int i = 0; i < 8; i++) {
        const int idx = base + i * 2048 + threadIdx.x * 8;
        float4 x0 = *(const float4*)(s + idx);
        float4 x1 = *(const float4*)(s + idx + 4);
        uint4 p;
        p.x = pack2bf(x0.x, x0.y); p.y = pack2bf(x0.z, x0.w);
        p.z = pack2bf(x1.x, x1.y); p.w = pack2bf(x1.z, x1.w);
        *(uint4*)(d + idx) = p;
    }
}

// ---------------- fused QKV projection (m97-style staging) ----------------
// all-bf16 A[4096,1024] x W[1024,1024]^T; unpadded 128x32 LDS tiles via
// global_load_lds width=16. z=0:Q z=1:K -> ws[b][h][t][dk]; z=2:V -> [b][h][dk][t]
// z=2 epilogue: 4 consecutive t per thread (quad*4+vv) packed into one 8B
// uint2 store (V^T is t-contiguous) -- replaces 64 scalar 2B stores/thread.
__global__ __launch_bounds__(256) void qkv_gemm(
    const u16* __restrict__ Qc, const u16* __restrict__ Kc,
    const u16* __restrict__ Vc,
    const u16* __restrict__ Wqc, const u16* __restrict__ Wkc,
    const u16* __restrict__ Wvc,
    const float* __restrict__ bq, const float* __restrict__ bk,
    const float* __restrict__ bv,
    u16* __restrict__ ws)
{
    __shared__ __align__(16) u16 As[128 * 32];
    __shared__ __align__(16) u16 Bs[128 * 32];
    const int z = blockIdx.z;
    const u16* A = (z == 0) ? Qc : (z == 1) ? Kc : Vc;
    const u16* W = (z == 0) ? Wqc : (z == 1) ? Wkc : Wvc;
    const float* bias = (z == 0) ? bq : (z == 1) ? bk : bv;
    u16* out = ws + (size_t)z * (size_t)BB * HH * TT * DKK;

    const int tid  = threadIdx.x;
    const int wave = tid >> 6, lane = tid & 63;
    const int quad = lane >> 4, l16 = lane & 15;
    const int wm = wave & 1, wn = wave >> 1;
    const int m0 = blockIdx.y * 128, n0 = blockIdx.x * 128;
    const int K = DD;

    // staging: call j covers rows j*64 + wave*16 .. +15; lane -> (row=l>>2, col=(l&3)*8)
    const int lrow = lane >> 2, lcol = (lane & 3) * 8;
    const u16* Ag0 = A + (size_t)(m0 + wave * 16 + lrow) * K + lcol;
    const u16* Ag1 = A + (size_t)(m0 + 64 + wave * 16 + lrow) * K + lcol;
    const u16* Wg0 = W + (size_t)(n0 + wave * 16 + lrow) * K + lcol;
    const u16* Wg1 = W + (size_t)(n0 + 64 + wave * 16 + lrow) * K + lcol;
    u16* AsD0 = &As[(wave * 16) * 32];
    u16* AsD1 = &As[(64 + wave * 16) * 32];
    u16* BsD0 = &Bs[(wave * 16) * 32];
    u16* BsD1 = &Bs[(64 + wave * 16) * 32];

    floatx4 acc[4][4];
    for (int i = 0; i < 4; i++)
        for (int j = 0; j < 4; j++)
            acc[i][j] = floatx4{0.f, 0.f, 0.f, 0.f};

    for (int k0 = 0; k0 < K; k0 += 32) {
        __syncthreads();
        gl2lds16(Ag0 + k0, AsD0);
        gl2lds16(Ag1 + k0, AsD1);
        gl2lds16(Wg0 + k0, BsD0);
        gl2lds16(Wg1 + k0, BsD1);
        __syncthreads();   // compiler emits vmcnt(0) drain before barrier

        bf16x8 af[4], bfr[4];
        for (int mi = 0; mi < 4; mi++)
            af[mi] = *(const bf16x8*)&As[(wm * 64 + mi * 16 + l16) * 32 + quad * 8];
        for (int ni = 0; ni < 4; ni++)
            bfr[ni] = *(const bf16x8*)&Bs[(wn * 64 + ni * 16 + l16) * 32 + quad * 8];
        for (int mi = 0; mi < 4; mi++)
            for (int ni = 0; ni < 4; ni++)
                acc[mi][ni] = __builtin_amdgcn_mfma_f32_16x16x32_bf16(
                    af[mi], bfr[ni], acc[mi][ni], 0, 0, 0);
    }

    for (int ni = 0; ni < 4; ni++) {
        const int n = n0 + wn * 64 + ni * 16 + l16;
        const float bv2 = bias[n];
        const int h = n >> 6, dk = n & 63;
        for (int mi = 0; mi < 4; mi++) {
            if (z == 2) {
                // 4 consecutive t -> one aligned 8B store into V^T
                const int m = m0 + wm * 64 + mi * 16 + quad * 4;
                const int b = m >> 11, t = m & 2047;
                uint2 pp;
                pp.x = pack2bf(acc[mi][ni][0] + bv2, acc[mi][ni][1] + bv2);
                pp.y = pack2bf(acc[mi][ni][2] + bv2, acc[mi][ni][3] + bv2);
                *(uint2*)&out[(((size_t)(b * HH + h)) * DKK + dk) * TT + t] = pp;
            } else {
                for (int vv = 0; vv < 4; vv++) {
                    const int m = m0 + wm * 64 + mi * 16 + quad * 4 + vv;
                    const int b = m >> 11, t = m & 2047;
                    out[(((size_t)(b * HH + h)) * TT + t) * DKK + dk] =
                        f2bf(acc[mi][ni][vv] + bv2);
                }
            }
        }
    }
}

// ---------------- output projection (m97-style staging) ----------------
__global__ __launch_bounds__(256) void out_gemm(
    const u16* __restrict__ Av, const u16* __restrict__ Wv,
    const float* __restrict__ bias, float* __restrict__ outv)
{
    __shared__ __align__(16) u16 As[128 * 32];
    __shared__ __align__(16) u16 Bs[128 * 32];
    const int tid  = threadIdx.x;
    const int wave = tid >> 6, lane = tid & 63;
    const int quad = lane >> 4, l16 = lane & 15;
    const int wm = wave & 1, wn = wave >> 1;
    const int m0 = blockIdx.y * 128, n0 = blockIdx.x * 128;
    const int K = DD, N = DD;

    const int lrow = lane >> 2, lcol = (lane & 3) * 8;
    const u16* Ag0 = Av + (size_t)(m0 + wave * 16 + lrow) * K + lcol;
    const u16* Ag1 = Av + (size_t)(m0 + 64 + wave * 16 + lrow) * K + lcol;
    const u16* Wg0 = Wv + (size_t)(n0 + wave * 16 + lrow) * K + lcol;
    const u16* Wg1 = Wv + (size_t)(n0 + 64 + wave * 16 + lrow) * K + lcol;
    u16* AsD0 = &As[(wave * 16) * 32];
    u16* AsD1 = &As[(64 + wave * 16) * 32];
    u16* BsD0 = &Bs[(wave * 16) * 32];
    u16* BsD1 = &Bs[(64 + wave * 16) * 32];

    floatx4 acc[4][4];
    for (int i = 0; i < 4; i++)
        for (int j = 0; j < 4; j++)
            acc[i][j] = floatx4{0.f, 0.f, 0.f, 0.f};

    for (int k0 = 0; k0 < K; k0 += 32) {
        __syncthreads();
        gl2lds16(Ag0 + k0, AsD0);
        gl2lds16(Ag1 + k0, AsD1);
        gl2lds16(Wg0 + k0, BsD0);
        gl2lds16(Wg1 + k0, BsD1);
        __syncthreads();

        bf16x8 af[4], bfr[4];
        for (int mi = 0; mi < 4; mi++)
            af[mi] = *(const bf16x8*)&As[(wm * 64 + mi * 16 + l16) * 32 + quad * 8];
        for (int ni = 0; ni < 4; ni++)
            bfr[ni] = *(const bf16x8*)&Bs[(wn * 64 + ni * 16 + l16) * 32 + quad * 8];
        for (int mi = 0; mi < 4; mi++)
            for (int ni = 0; ni < 4; ni++)
                acc[mi][ni] = __builtin_amdgcn_mfma_f32_16x16x32_bf16(
                    af[mi], bfr[ni], acc[mi][ni], 0, 0, 0);
    }

    for (int ni = 0; ni < 4; ni++) {
        const int n = n0 + wn * 64 + ni * 16 + l16;
        const float bv2 = bias[n];
        for (int mi = 0; mi < 4; mi++)
            for (int vv = 0; vv < 4; vv++) {
                const int m = m0 + wm * 64 + mi * 16 + quad * 4 + vv;
                outv[(size_t)m * N + n] = acc[mi][ni][vv] + bv2;
            }
    }
}

// ---------------- flash attention: 8 waves x 16 q-rows, swizzled LDS ------
// R4 structure (grid 512 x 512 thr -> 16 waves/CU, reg-staged K/V, in-reg P)
// + R6's verified zero-conflict XOR granule swizzle: LDS [64][64] u16 rows,
// LDS[r][g] holds global granule g^(r&7); reads use rg = (j^(l16&7))*8.
// Legal because staging is reg->ds_write (both sides swizzled, rule #21).
__global__ __launch_bounds__(512) void attn_kernel(
    const u16* __restrict__ Qp, const u16* __restrict__ Kp,
    const u16* __restrict__ Vpt, const int* __restrict__ mask,
    u16* __restrict__ Xa)
{
    __shared__ __align__(16) u16 Ks[64 * 64];     // [key][dk] swizzled
    __shared__ __align__(16) u16 Vs[64 * 64];     // [dk][key] swizzled
    const int tid  = threadIdx.x;
    const int wave = tid >> 6, lane = tid & 63;
    const int quad = lane >> 4, l16 = lane & 15;
    const int bid = blockIdx.x;
    const int qt = bid & 15, bh = bid >> 4;
    const int b = bh >> 4, h = bh & 15;
    const int qbase = qt * 128 + wave * 16;

    const u16* Qb = Qp + (size_t)bh * TT * DKK;
    const u16* Kb = Kp + (size_t)bh * TT * DKK;
    const u16* Vb = Vpt + (size_t)bh * DKK * TT;
    const int* mk = mask + b * TT;

    // staging: 512 thr = 64 rows x 8 granules(16B); source granule
    // pre-swizzled so LDS[r][g] = global[r][g^(r&7)], LDS dest linear.
    const int srow = tid >> 3, sg = tid & 7;
    const int sgs = sg ^ (srow & 7);
    const u16* Ksrc = Kb + (size_t)srow * DKK + sgs * 8;
    const u16* Vsrc = Vb + (size_t)srow * TT + sgs * 8;
    u16* KsD = &Ks[srow * 64 + sg * 8];
    u16* VsD = &Vs[srow * 64 + sg * 8];

    // swizzled read offsets: frag rows have row&7 == l16&7
    const int x7 = l16 & 7;
    const int rg0 = (quad ^ x7) * 8;          // logical granule j = quad
    const int rg1 = ((quad + 4) ^ x7) * 8;    // logical granule j = quad+4

    const bf16x8 qf0 = *(const bf16x8*)&Qb[(size_t)(qbase + l16) * DKK + quad * 8];
    const bf16x8 qf1 = *(const bf16x8*)&Qb[(size_t)(qbase + l16) * DKK + 32 + quad * 8];

    floatx4 o[4];
    for (int i = 0; i < 4; i++) o[i] = floatx4{0.f, 0.f, 0.f, 0.f};
    float rs = 0.f;   // partial softmax denom (this quad's keys)

    uint4 kr = *(const uint4*)Ksrc;
    uint4 vr = *(const uint4*)Vsrc;

    for (int ti = 0; ti < TT / 64; ti++) {
        const int k0 = ti * 64;
        __syncthreads();   // all waves done reading prev tile
        *(uint4*)KsD = kr;
        *(uint4*)VsD = vr;
        __syncthreads();
        if (ti + 1 < TT / 64) {
            kr = *(const uint4*)(Ksrc + (size_t)(k0 + 64) * DKK);
            vr = *(const uint4*)(Vsrc + (k0 + 64));
        }

        const int mv0 = mk[k0 + l16];
        const int mv1 = mk[k0 + 16 + l16];
        const int mv2 = mk[k0 + 32 + l16];
        const int mv3 = mk[k0 + 48 + l16];
        if (!__any(mv0 | mv1 | mv2 | mv3)) continue;   // block-uniform
        const bool allv = __all(mv0 && mv1 && mv2 && mv3);

        bf16x8 kf[4][2];
        #pragma unroll
        for (int c = 0; c < 4; c++) {
            const u16* kb = &Ks[(c * 16 + l16) * 64];
            kf[c][0] = *(const bf16x8*)&kb[rg0];
            kf[c][1] = *(const bf16x8*)&kb[rg1];
        }

        // swapped QK^T: S^T in regs -- lane(quad,l16) holds
        // P[key=c*16+quad*4+v][qrow=l16]
        floatx4 s[4];
        #pragma unroll
        for (int c = 0; c < 4; c++) s[c] = floatx4{0.f, 0.f, 0.f, 0.f};
        #pragma unroll
        for (int c = 0; c < 4; c++) {
            s[c] = __builtin_amdgcn_mfma_f32_16x16x32_bf16(kf[c][0], qf0, s[c], 0, 0, 0);
            s[c] = __builtin_amdgcn_mfma_f32_16x16x32_bf16(kf[c][1], qf1, s[c], 0, 0, 0);
        }

        float p[4][4];
        if (allv) {
            #pragma unroll
            for (int c = 0; c < 4; c++)
                #pragma unroll
                for (int v = 0; v < 4; v++)
                    p[c][v] = __expf(s[c][v] * 0.125f);
        } else {
            #pragma unroll
            for (int c = 0; c < 4; c++)
                #pragma unroll
                for (int v = 0; v < 4; v++)
                    p[c][v] = mk[k0 + c * 16 + quad * 4 + v]
                                  ? __expf(s[c][v] * 0.125f) : 0.f;
        }
        #pragma unroll
        for (int c = 0; c < 4; c++)
            #pragma unroll
            for (int v = 0; v < 4; v++)
                rs += p[c][v];

        // in-register gather to PV A-frags (cvt_pk + permlane swaps)
        u32 A0 = cvtpk_bf16(p[0][0], p[0][1]), B0 = cvtpk_bf16(p[1][0], p[1][1]);
        u32 A1 = cvtpk_bf16(p[0][2], p[0][3]), B1 = cvtpk_bf16(p[1][2], p[1][3]);
        u32 A2 = cvtpk_bf16(p[2][0], p[2][1]), B2 = cvtpk_bf16(p[3][0], p[3][1]);
        u32 A3 = cvtpk_bf16(p[2][2], p[2][3]), B3 = cvtpk_bf16(p[3][2], p[3][3]);
        quad_gather(A0, B0);
        quad_gather(A1, B1);
        quad_gather(A2, B2);
        quad_gather(A3, B3);
        union { u32 w[4]; bf16x8 v; } pa0, pa1;
        pa0.w[0] = A0; pa0.w[1] = A1; pa0.w[2] = B0; pa0.w[3] = B1;  // keys 0-31
        pa1.w[0] = A2; pa1.w[1] = A3; pa1.w[2] = B2; pa1.w[3] = B3;  // keys 32-63

        #pragma unroll
        for (int nb = 0; nb < 4; nb++) {
            const u16* vb = &Vs[(nb * 16 + l16) * 64];
            const bf16x8 vf0 = *(const bf16x8*)&vb[rg0];
            const bf16x8 vf1 = *(const bf16x8*)&vb[rg1];
            o[nb] = __builtin_amdgcn_mfma_f32_16x16x32_bf16(pa0.v, vf0, o[nb], 0, 0, 0);
            o[nb] = __builtin_amdgcn_mfma_f32_16x16x32_bf16(pa1.v, vf1, o[nb], 0, 0, 0);
        }
    }

    // denom: combine the 4 quads' partials, then pull per-output-row values
    rs += __shfl_xor(rs, 16, 64);
    rs += __shfl_xor(rs, 32, 64);
    float inv[4];
    #pragma unroll
    for (int v = 0; v < 4; v++)
        inv[v] = 1.0f / __shfl(rs, quad * 4 + v, 64);

    #pragma unroll
    for (int nb = 0; nb < 4; nb++)
        #pragma unroll
        for (int v = 0; v < 4; v++) {
            const int t = qbase + quad * 4 + v;
            Xa[((size_t)b * TT + t) * DD + h * DKK + nb * 16 + l16] =
                f2bf(o[nb][v] * inv[v]);
        }
}

extern "C" void kernel_launch(void* const* d_in, const int* in_sizes, int n_in,
                              void* d_out, int out_size, void* d_ws, size_t ws_size,
                              hipStream_t stream) {
    const float* q    = (const float*)d_in[0];
    const float* k    = (const float*)d_in[1];
    const float* v    = (const float*)d_in[2];
    const int*   mask = (const int*)d_in[3];
    const float* Wq   = (const float*)d_in[4];
    const float* bq   = (const float*)d_in[5];
    const float* Wk   = (const float*)d_in[6];
    const float* bk   = (const float*)d_in[7];
    const float* Wv   = (const float*)d_in[8];
    const float* bv   = (const float*)d_in[9];
    const float* Wo   = (const float*)d_in[10];
    const float* bo   = (const float*)d_in[11];

    // ws layout (u16 elems): Qc|Kc|Vc (4M each) | Wqc|Wkc|Wvc|Woc (1M each)
    //                        | Qp|Kp|Vpt|Xa (4M each)  = 64 MB total
    u16* Qc  = (u16*)d_ws;
    u16* Kc  = Qc + (size_t)ACT;
    u16* Vc  = Kc + (size_t)ACT;
    u16* Wqc = Vc + (size_t)ACT;
    u16* Wkc = Wqc + (size_t)WTE;
    u16* Wvc = Wkc + (size_t)WTE;
    u16* Woc = Wvc + (size_t)WTE;
    u16* Qp  = Woc + (size_t)WTE;
    u16* Kp  = Qp + (size_t)ACT;
    u16* Vpt = Kp + (size_t)ACT;
    u16* Xa  = Vpt + (size_t)ACT;

    CvtArgs ca;
    ca.src[0] = q;  ca.dst[0] = Qc;
    ca.src[1] = k;  ca.dst[1] = Kc;
    ca.src[2] = v;  ca.dst[2] = Vc;
    ca.src[3] = Wq; ca.dst[3] = Wqc;
    ca.src[4] = Wk; ca.dst[4] = Wkc;
    ca.src[5] = Wv; ca.dst[5] = Wvc;
    ca.src[6] = Wo; ca.dst[6] = Woc;
    convert_bf16<<<1024, 256, 0, stream>>>(ca);

    qkv_gemm<<<dim3(DD / 128, (BB * TT) / 128, 3), 256, 0, stream>>>(
        Qc, Kc, Vc, Wqc, Wkc, Wvc, bq, bk, bv, Qp);

    attn_kernel<<<dim3(BB * HH * (TT / 128)), 512, 0, stream>>>(Qp, Kp, Vpt, mask, Xa);

    out_gemm<<<dim3(DD / 128, (BB * TT) / 128), 256, 0, stream>>>(Xa, Woc, bo, (float*)d_out);
}

// Round 8
// 234.314 us; speedup vs baseline: 1.0623x; 1.0477x over previous
//
#include <hip/hip_runtime.h>

typedef unsigned short u16;
typedef unsigned int u32;
typedef __bf16 bf16x8 __attribute__((ext_vector_type(8)));
typedef float floatx4 __attribute__((ext_vector_type(4)));

#define BB 2
#define TT 2048
#define DD 1024
#define HH 16
#define DKK 64
#define ACT (BB * TT * DD)      // 4194304 elements
#define WTE (DD * DD)           // 1048576 elements

__device__ inline u16 f2bf(float f) {
    union { float f; u32 u; } c; c.f = f;
    u32 r = (c.u + 0x7fffu + ((c.u >> 16) & 1u)) >> 16;
    return (u16)r;
}
__device__ inline u32 pack2bf(float a, float b) {
    return (u32)f2bf(a) | ((u32)f2bf(b) << 16);
}

// async global->LDS, 16B per lane; LDS dest = wave-uniform base + lane*16
typedef __attribute__((address_space(1))) const u32 gas_u32;
typedef __attribute__((address_space(3))) u32 las_u32;
__device__ __forceinline__ void gl2lds16(const u16* g, u16* l) {
    __builtin_amdgcn_global_load_lds((gas_u32*)g, (las_u32*)l, 16, 0, 0);
}

// pack 2 f32 -> 1 u32 of 2 bf16 (RNE), single VALU op (guide T12 recipe)
__device__ __forceinline__ u32 cvtpk_bf16(float lo, float hi) {
    u32 r;
    asm("v_cvt_pk_bf16_f32 %0, %1, %2" : "=v"(r) : "v"(lo), "v"(hi));
    return r;
}

// swap32 then swap16 between two VGPRs (quad = 16-lane group):
//   after: a = {a.q0, a.q2, b.q0, b.q2}, b = {a.q1, a.q3, b.q1, b.q3}
// s_nop guards the VALU->permlane wait-state conservatively.
__device__ __forceinline__ void quad_gather(u32 &a, u32 &b) {
    asm volatile("s_nop 1\n\t"
                 "v_permlane32_swap_b32 %0, %1\n\t"
                 "s_nop 1\n\t"
                 "v_permlane16_swap_b32 %0, %1"
                 : "+v"(a), "+v"(b));
}

// ---------------- fp32 -> bf16 convert pass ----------------
// t=0..2: activations (256 blocks x 16384 floats); t=3..6: weights (64 blocks)
struct CvtArgs { const float* src[7]; u16* dst[7]; };
__global__ __launch_bounds__(256) void convert_bf16(CvtArgs a) {
    int bid = blockIdx.x, t, local;
    if (bid < 768) { t = bid >> 8; local = bid & 255; }
    else { int r = bid - 768; t = 3 + (r >> 6); local = r & 63; }
    const float* s = a.src[t];
    u16* d = a.dst[t];
    const int base = local * 16384;
    for (int i = 0; i < 8; i++) {
        const int idx = base + i * 2048 + threadIdx.x * 8;
        float4 x0 = *(const float4*)(s + idx);
        float4 x1 = *(const float4*)(s + idx + 4);
        uint4 p;
        p.x = pack2bf(x0.x, x0.y); p.y = pack2bf(x0.z, x0.w);
        p.z = pack2bf(x1.x, x1.y); p.w = pack2bf(x1.z, x1.w);
        *(uint4*)(d + idx) = p;
    }
}

// ---------------- fused QKV projection (m97-style staging) ----------------
// all-bf16 A[4096,1024] x W[1024,1024]^T; unpadded 128x32 LDS tiles via
// global_load_lds width=16. z=0:Q z=1:K -> ws[b][h][t][dk]; z=2:V -> [b][h][dk][t]
// grid = 768 1-D with XCD-bijective swizzle (768 = 8 XCD x 96): each XCD gets
// 96 logically consecutive blocks = 12 A-panels x 8 n-blocks, so A-panels are
// fetched once per XCD and the 2MB W slice stays L2-resident (T1; R7 FETCH
// was 101MB vs ~30MB ideal from round-robin panel scatter).
__global__ __launch_bounds__(256) void qkv_gemm(
    const u16* __restrict__ Qc, const u16* __restrict__ Kc,
    const u16* __restrict__ Vc,
    const u16* __restrict__ Wqc, const u16* __restrict__ Wkc,
    const u16* __restrict__ Wvc,
    const float* __restrict__ bq, const float* __restrict__ bk,
    const float* __restrict__ bv,
    u16* __restrict__ ws)
{
    __shared__ __align__(16) u16 As[128 * 32];
    __shared__ __align__(16) u16 Bs[128 * 32];
    // XCD swizzle: logical id l; XCD (bid&7) owns l in [ (bid&7)*96, +96 )
    const int l = (blockIdx.x & 7) * 96 + (blockIdx.x >> 3);
    const int z = l >> 8;              // 256 logical blocks per slice
    const int yy = (l & 255) >> 3;     // m-panel (A rows), 32 per slice
    const int xx = l & 7;              // n-panel (W rows), 8 per slice
    const u16* A = (z == 0) ? Qc : (z == 1) ? Kc : Vc;
    const u16* W = (z == 0) ? Wqc : (z == 1) ? Wkc : Wvc;
    const float* bias = (z == 0) ? bq : (z == 1) ? bk : bv;
    u16* out = ws + (size_t)z * (size_t)BB * HH * TT * DKK;

    const int tid  = threadIdx.x;
    const int wave = tid >> 6, lane = tid & 63;
    const int quad = lane >> 4, l16 = lane & 15;
    const int wm = wave & 1, wn = wave >> 1;
    const int m0 = yy * 128, n0 = xx * 128;
    const int K = DD;

    // staging: call j covers rows j*64 + wave*16 .. +15; lane -> (row=l>>2, col=(l&3)*8)
    const int lrow = lane >> 2, lcol = (lane & 3) * 8;
    const u16* Ag0 = A + (size_t)(m0 + wave * 16 + lrow) * K + lcol;
    const u16* Ag1 = A + (size_t)(m0 + 64 + wave * 16 + lrow) * K + lcol;
    const u16* Wg0 = W + (size_t)(n0 + wave * 16 + lrow) * K + lcol;
    const u16* Wg1 = W + (size_t)(n0 + 64 + wave * 16 + lrow) * K + lcol;
    u16* AsD0 = &As[(wave * 16) * 32];
    u16* AsD1 = &As[(64 + wave * 16) * 32];
    u16* BsD0 = &Bs[(wave * 16) * 32];
    u16* BsD1 = &Bs[(64 + wave * 16) * 32];

    floatx4 acc[4][4];
    for (int i = 0; i < 4; i++)
        for (int j = 0; j < 4; j++)
            acc[i][j] = floatx4{0.f, 0.f, 0.f, 0.f};

    for (int k0 = 0; k0 < K; k0 += 32) {
        __syncthreads();
        gl2lds16(Ag0 + k0, AsD0);
        gl2lds16(Ag1 + k0, AsD1);
        gl2lds16(Wg0 + k0, BsD0);
        gl2lds16(Wg1 + k0, BsD1);
        __syncthreads();   // compiler emits vmcnt(0) drain before barrier

        bf16x8 af[4], bfr[4];
        for (int mi = 0; mi < 4; mi++)
            af[mi] = *(const bf16x8*)&As[(wm * 64 + mi * 16 + l16) * 32 + quad * 8];
        for (int ni = 0; ni < 4; ni++)
            bfr[ni] = *(const bf16x8*)&Bs[(wn * 64 + ni * 16 + l16) * 32 + quad * 8];
        for (int mi = 0; mi < 4; mi++)
            for (int ni = 0; ni < 4; ni++)
                acc[mi][ni] = __builtin_amdgcn_mfma_f32_16x16x32_bf16(
                    af[mi], bfr[ni], acc[mi][ni], 0, 0, 0);
    }

    for (int ni = 0; ni < 4; ni++) {
        const int n = n0 + wn * 64 + ni * 16 + l16;
        const float bv2 = bias[n];
        const int h = n >> 6, dk = n & 63;
        for (int mi = 0; mi < 4; mi++) {
            if (z == 2) {
                // 4 consecutive t -> one aligned 8B store into V^T
                const int m = m0 + wm * 64 + mi * 16 + quad * 4;
                const int b = m >> 11, t = m & 2047;
                uint2 pp;
                pp.x = pack2bf(acc[mi][ni][0] + bv2, acc[mi][ni][1] + bv2);
                pp.y = pack2bf(acc[mi][ni][2] + bv2, acc[mi][ni][3] + bv2);
                *(uint2*)&out[(((size_t)(b * HH + h)) * DKK + dk) * TT + t] = pp;
            } else {
                for (int vv = 0; vv < 4; vv++) {
                    const int m = m0 + wm * 64 + mi * 16 + quad * 4 + vv;
                    const int b = m >> 11, t = m & 2047;
                    out[(((size_t)(b * HH + h)) * TT + t) * DKK + dk] =
                        f2bf(acc[mi][ni][vv] + bv2);
                }
            }
        }
    }
}

// ---------------- output projection (m97-style staging) ----------------
// grid = 256 1-D, XCD-bijective swizzle (256 = 8 x 32): chunk = 4 A-panels
// x 8 n-blocks per XCD; Woc (2MB) L2-resident per XCD.
__global__ __launch_bounds__(256) void out_gemm(
    const u16* __restrict__ Av, const u16* __restrict__ Wv,
    const float* __restrict__ bias, float* __restrict__ outv)
{
    __shared__ __align__(16) u16 As[128 * 32];
    __shared__ __align__(16) u16 Bs[128 * 32];
    const int l = (blockIdx.x & 7) * 32 + (blockIdx.x >> 3);
    const int yy = l >> 3, xx = l & 7;
    const int tid  = threadIdx.x;
    const int wave = tid >> 6, lane = tid & 63;
    const int quad = lane >> 4, l16 = lane & 15;
    const int wm = wave & 1, wn = wave >> 1;
    const int m0 = yy * 128, n0 = xx * 128;
    const int K = DD, N = DD;

    const int lrow = lane >> 2, lcol = (lane & 3) * 8;
    const u16* Ag0 = Av + (size_t)(m0 + wave * 16 + lrow) * K + lcol;
    const u16* Ag1 = Av + (size_t)(m0 + 64 + wave * 16 + lrow) * K + lcol;
    const u16* Wg0 = Wv + (size_t)(n0 + wave * 16 + lrow) * K + lcol;
    const u16* Wg1 = Wv + (size_t)(n0 + 64 + wave * 16 + lrow) * K + lcol;
    u16* AsD0 = &As[(wave * 16) * 32];
    u16* AsD1 = &As[(64 + wave * 16) * 32];
    u16* BsD0 = &Bs[(wave * 16) * 32];
    u16* BsD1 = &Bs[(64 + wave * 16) * 32];

    floatx4 acc[4][4];
    for (int i = 0; i < 4; i++)
        for (int j = 0; j < 4; j++)
            acc[i][j] = floatx4{0.f, 0.f, 0.f, 0.f};

    for (int k0 = 0; k0 < K; k0 += 32) {
        __syncthreads();
        gl2lds16(Ag0 + k0, AsD0);
        gl2lds16(Ag1 + k0, AsD1);
        gl2lds16(Wg0 + k0, BsD0);
        gl2lds16(Wg1 + k0, BsD1);
        __syncthreads();

        bf16x8 af[4], bfr[4];
        for (int mi = 0; mi < 4; mi++)
            af[mi] = *(const bf16x8*)&As[(wm * 64 + mi * 16 + l16) * 32 + quad * 8];
        for (int ni = 0; ni < 4; ni++)
            bfr[ni] = *(const bf16x8*)&Bs[(wn * 64 + ni * 16 + l16) * 32 + quad * 8];
        for (int mi = 0; mi < 4; mi++)
            for (int ni = 0; ni < 4; ni++)
                acc[mi][ni] = __builtin_amdgcn_mfma_f32_16x16x32_bf16(
                    af[mi], bfr[ni], acc[mi][ni], 0, 0, 0);
    }

    for (int ni = 0; ni < 4; ni++) {
        const int n = n0 + wn * 64 + ni * 16 + l16;
        const float bv2 = bias[n];
        for (int mi = 0; mi < 4; mi++)
            for (int vv = 0; vv < 4; vv++) {
                const int m = m0 + wm * 64 + mi * 16 + quad * 4 + vv;
                outv[(size_t)m * N + n] = acc[mi][ni][vv] + bv2;
            }
    }
}

// ---------------- flash attention: 8 waves x 16 q-rows, swizzled LDS ------
// R4 structure (grid 512 x 512 thr -> 16 waves/CU, reg-staged K/V, in-reg P)
// + R6's verified zero-conflict XOR granule swizzle: LDS [64][64] u16 rows,
// LDS[r][g] holds global granule g^(r&7); reads use rg = (j^(l16&7))*8.
// Legal because staging is reg->ds_write (both sides swizzled, rule #21).
__global__ __launch_bounds__(512) void attn_kernel(
    const u16* __restrict__ Qp, const u16* __restrict__ Kp,
    const u16* __restrict__ Vpt, const int* __restrict__ mask,
    u16* __restrict__ Xa)
{
    __shared__ __align__(16) u16 Ks[64 * 64];     // [key][dk] swizzled
    __shared__ __align__(16) u16 Vs[64 * 64];     // [dk][key] swizzled
    const int tid  = threadIdx.x;
    const int wave = tid >> 6, lane = tid & 63;
    const int quad = lane >> 4, l16 = lane & 15;
    const int bid = blockIdx.x;
    const int qt = bid & 15, bh = bid >> 4;
    const int b = bh >> 4, h = bh & 15;
    const int qbase = qt * 128 + wave * 16;

    const u16* Qb = Qp + (size_t)bh * TT * DKK;
    const u16* Kb = Kp + (size_t)bh * TT * DKK;
    const u16* Vb = Vpt + (size_t)bh * DKK * TT;
    const int* mk = mask + b * TT;

    // staging: 512 thr = 64 rows x 8 granules(16B); source granule
    // pre-swizzled so LDS[r][g] = global[r][g^(r&7)], LDS dest linear.
    const int srow = tid >> 3, sg = tid & 7;
    const int sgs = sg ^ (srow & 7);
    const u16* Ksrc = Kb + (size_t)srow * DKK + sgs * 8;
    const u16* Vsrc = Vb + (size_t)srow * TT + sgs * 8;
    u16* KsD = &Ks[srow * 64 + sg * 8];
    u16* VsD = &Vs[srow * 64 + sg * 8];

    // swizzled read offsets: frag rows have row&7 == l16&7
    const int x7 = l16 & 7;
    const int rg0 = (quad ^ x7) * 8;          // logical granule j = quad
    const int rg1 = ((quad + 4) ^ x7) * 8;    // logical granule j = quad+4

    const bf16x8 qf0 = *(const bf16x8*)&Qb[(size_t)(qbase + l16) * DKK + quad * 8];
    const bf16x8 qf1 = *(const bf16x8*)&Qb[(size_t)(qbase + l16) * DKK + 32 + quad * 8];

    floatx4 o[4];
    for (int i = 0; i < 4; i++) o[i] = floatx4{0.f, 0.f, 0.f, 0.f};
    float rs = 0.f;   // partial softmax denom (this quad's keys)

    uint4 kr = *(const uint4*)Ksrc;
    uint4 vr = *(const uint4*)Vsrc;

    for (int ti = 0; ti < TT / 64; ti++) {
        const int k0 = ti * 64;
        __syncthreads();   // all waves done reading prev tile
        *(uint4*)KsD = kr;
        *(uint4*)VsD = vr;
        __syncthreads();
        if (ti + 1 < TT / 64) {
            kr = *(const uint4*)(Ksrc + (size_t)(k0 + 64) * DKK);
            vr = *(const uint4*)(Vsrc + (k0 + 64));
        }

        const int mv0 = mk[k0 + l16];
        const int mv1 = mk[k0 + 16 + l16];
        const int mv2 = mk[k0 + 32 + l16];
        const int mv3 = mk[k0 + 48 + l16];
        if (!__any(mv0 | mv1 | mv2 | mv3)) continue;   // block-uniform
        const bool allv = __all(mv0 && mv1 && mv2 && mv3);

        bf16x8 kf[4][2];
        #pragma unroll
        for (int c = 0; c < 4; c++) {
            const u16* kb = &Ks[(c * 16 + l16) * 64];
            kf[c][0] = *(const bf16x8*)&kb[rg0];
            kf[c][1] = *(const bf16x8*)&kb[rg1];
        }

        // swapped QK^T: S^T in regs -- lane(quad,l16) holds
        // P[key=c*16+quad*4+v][qrow=l16]
        floatx4 s[4];
        #pragma unroll
        for (int c = 0; c < 4; c++) s[c] = floatx4{0.f, 0.f, 0.f, 0.f};
        #pragma unroll
        for (int c = 0; c < 4; c++) {
            s[c] = __builtin_amdgcn_mfma_f32_16x16x32_bf16(kf[c][0], qf0, s[c], 0, 0, 0);
            s[c] = __builtin_amdgcn_mfma_f32_16x16x32_bf16(kf[c][1], qf1, s[c], 0, 0, 0);
        }

        float p[4][4];
        if (allv) {
            #pragma unroll
            for (int c = 0; c < 4; c++)
                #pragma unroll
                for (int v = 0; v < 4; v++)
                    p[c][v] = __expf(s[c][v] * 0.125f);
        } else {
            #pragma unroll
            for (int c = 0; c < 4; c++)
                #pragma unroll
                for (int v = 0; v < 4; v++)
                    p[c][v] = mk[k0 + c * 16 + quad * 4 + v]
                                  ? __expf(s[c][v] * 0.125f) : 0.f;
        }
        #pragma unroll
        for (int c = 0; c < 4; c++)
            #pragma unroll
            for (int v = 0; v < 4; v++)
                rs += p[c][v];

        // in-register gather to PV A-frags (cvt_pk + permlane swaps)
        u32 A0 = cvtpk_bf16(p[0][0], p[0][1]), B0 = cvtpk_bf16(p[1][0], p[1][1]);
        u32 A1 = cvtpk_bf16(p[0][2], p[0][3]), B1 = cvtpk_bf16(p[1][2], p[1][3]);
        u32 A2 = cvtpk_bf16(p[2][0], p[2][1]), B2 = cvtpk_bf16(p[3][0], p[3][1]);
        u32 A3 = cvtpk_bf16(p[2][2], p[2][3]), B3 = cvtpk_bf16(p[3][2], p[3][3]);
        quad_gather(A0, B0);
        quad_gather(A1, B1);
        quad_gather(A2, B2);
        quad_gather(A3, B3);
        union { u32 w[4]; bf16x8 v; } pa0, pa1;
        pa0.w[0] = A0; pa0.w[1] = A1; pa0.w[2] = B0; pa0.w[3] = B1;  // keys 0-31
        pa1.w[0] = A2; pa1.w[1] = A3; pa1.w[2] = B2; pa1.w[3] = B3;  // keys 32-63

        #pragma unroll
        for (int nb = 0; nb < 4; nb++) {
            const u16* vb = &Vs[(nb * 16 + l16) * 64];
            const bf16x8 vf0 = *(const bf16x8*)&vb[rg0];
            const bf16x8 vf1 = *(const bf16x8*)&vb[rg1];
            o[nb] = __builtin_amdgcn_mfma_f32_16x16x32_bf16(pa0.v, vf0, o[nb], 0, 0, 0);
            o[nb] = __builtin_amdgcn_mfma_f32_16x16x32_bf16(pa1.v, vf1, o[nb], 0, 0, 0);
        }
    }

    // denom: combine the 4 quads' partials, then pull per-output-row values
    rs += __shfl_xor(rs, 16, 64);
    rs += __shfl_xor(rs, 32, 64);
    float inv[4];
    #pragma unroll
    for (int v = 0; v < 4; v++)
        inv[v] = 1.0f / __shfl(rs, quad * 4 + v, 64);

    #pragma unroll
    for (int nb = 0; nb < 4; nb++)
        #pragma unroll
        for (int v = 0; v < 4; v++) {
            const int t = qbase + quad * 4 + v;
            Xa[((size_t)b * TT + t) * DD + h * DKK + nb * 16 + l16] =
                f2bf(o[nb][v] * inv[v]);
        }
}

extern "C" void kernel_launch(void* const* d_in, const int* in_sizes, int n_in,
                              void* d_out, int out_size, void* d_ws, size_t ws_size,
                              hipStream_t stream) {
    const float* q    = (const float*)d_in[0];
    const float* k    = (const float*)d_in[1];
    const float* v    = (const float*)d_in[2];
    const int*   mask = (const int*)d_in[3];
    const float* Wq   = (const float*)d_in[4];
    const float* bq   = (const float*)d_in[5];
    const float* Wk   = (const float*)d_in[6];
    const float* bk   = (const float*)d_in[7];
    const float* Wv   = (const float*)d_in[8];
    const float* bv   = (const float*)d_in[9];
    const float* Wo   = (const float*)d_in[10];
    const float* bo   = (const float*)d_in[11];

    // ws layout (u16 elems): Qc|Kc|Vc (4M each) | Wqc|Wkc|Wvc|Woc (1M each)
    //                        | Qp|Kp|Vpt|Xa (4M each)  = 64 MB total
    u16* Qc  = (u16*)d_ws;
    u16* Kc  = Qc + (size_t)ACT;
    u16* Vc  = Kc + (size_t)ACT;
    u16* Wqc = Vc + (size_t)ACT;
    u16* Wkc = Wqc + (size_t)WTE;
    u16* Wvc = Wkc + (size_t)WTE;
    u16* Woc = Wvc + (size_t)WTE;
    u16* Qp  = Woc + (size_t)WTE;
    u16* Kp  = Qp + (size_t)ACT;
    u16* Vpt = Kp + (size_t)ACT;
    u16* Xa  = Vpt + (size_t)ACT;

    CvtArgs ca;
    ca.src[0] = q;  ca.dst[0] = Qc;
    ca.src[1] = k;  ca.dst[1] = Kc;
    ca.src[2] = v;  ca.dst[2] = Vc;
    ca.src[3] = Wq; ca.dst[3] = Wqc;
    ca.src[4] = Wk; ca.dst[4] = Wkc;
    ca.src[5] = Wv; ca.dst[5] = Wvc;
    ca.src[6] = Wo; ca.dst[6] = Woc;
    convert_bf16<<<1024, 256, 0, stream>>>(ca);

    qkv_gemm<<<dim3(768), 256, 0, stream>>>(
        Qc, Kc, Vc, Wqc, Wkc, Wvc, bq, bk, bv, Qp);

    attn_kernel<<<dim3(BB * HH * (TT / 128)), 512, 0, stream>>>(Qp, Kp, Vpt, mask, Xa);

    out_gemm<<<dim3(256), 256, 0, stream>>>(Xa, Woc, bo, (float*)d_out);
}